// Round 5
// baseline (1403.248 us; speedup 1.0000x reference)
//
#include <hip/hip_runtime.h>
#include <math.h>

// RelationMessagePassing — bf16 MFMA + CHUNKED counting-sort scatter.
//
// Round-4 finding: ws_size < 283 MB, so the un-chunked CSR msgbuf never ran
// (profile showed the Lb0 fallback). This round chunks the CSR pipeline per
// relation so msgbuf fits whatever ws_size provides:
//   fixed ws: gmax|hist|nodeStart|partial|cursor|exps|statesb|weights (~40 MB)
//   msgbuf: remaining ws; capacity C participants = rem/128B
//   per relation, per chunk of C/A tuples:
//     memset hist -> hist_k -> scanA/scanB/scanC (nodeStart,cursor)
//     -> rel_mfma<D,true>: MFMA MLP, msgbuf[atomicAdd(cursor[node],1)*64+f]
//        = fp16(exp(8*o_f)), atomicMax(gmax)
//     -> reduce_accum: exps[node][f] += sum(segment)   (no fp atomics)
//   then up_mfma: max_msg = log(1e-16+S*e^-8M)/8+M; concat; MFMA; fp32 out.
// If >16 chunks needed (tiny ws): round-3 atomic fallback (known passing).

typedef __attribute__((ext_vector_type(8))) short bf16x8;
typedef __attribute__((ext_vector_type(4))) float f32x4;
typedef unsigned short u16;

__device__ __forceinline__ unsigned f2ord(float f) {
    unsigned u = __float_as_uint(f);
    return (u & 0x80000000u) ? ~u : (u | 0x80000000u);
}
__device__ __forceinline__ float ord2f(unsigned u) {
    return (u & 0x80000000u) ? __uint_as_float(u & 0x7fffffffu) : __uint_as_float(~u);
}
__device__ __forceinline__ u16 f2bf(float f) {
    unsigned u = __float_as_uint(f);
    return (u16)((u + 0x7fffu + ((u >> 16) & 1u)) >> 16);
}

// ---------------- prep ----------------
__global__ __launch_bounds__(256) void conv_states(const float* __restrict__ src,
                                                   u16* __restrict__ dst, int n8) {
    int i = blockIdx.x * 256 + threadIdx.x;
    if (i >= n8) return;
    float4 a = reinterpret_cast<const float4*>(src)[2 * i];
    float4 b = reinterpret_cast<const float4*>(src)[2 * i + 1];
    bf16x8 v;
    v[0] = (short)f2bf(a.x); v[1] = (short)f2bf(a.y);
    v[2] = (short)f2bf(a.z); v[3] = (short)f2bf(a.w);
    v[4] = (short)f2bf(b.x); v[5] = (short)f2bf(b.y);
    v[6] = (short)f2bf(b.z); v[7] = (short)f2bf(b.w);
    reinterpret_cast<bf16x8*>(dst)[i] = v;
}

struct TEnt { const float* src; u16* dst; int K, N, base; };
struct TPack { TEnt e[8]; };
__global__ __launch_bounds__(256) void transpose_w(TPack p) {
    int b = blockIdx.x;
    int i = 0;
    while (i < 7 && b >= p.e[i + 1].base) ++i;
    TEnt e = p.e[i];
    int idx = (b - e.base) * 256 + threadIdx.x;
    if (idx < e.K * e.N) {
        int n = idx / e.K, k = idx - n * e.K;
        e.dst[idx] = f2bf(e.src[k * e.N + n]);
    }
}

// ---------------- sort machinery ----------------
__global__ __launch_bounds__(256) void hist_k(const int* __restrict__ idx, int n,
                                              int* __restrict__ hist) {
    int i = blockIdx.x * 256 + threadIdx.x;
    if (i < n) atomicAdd(&hist[idx[i]], 1);
}

__global__ __launch_bounds__(256) void scanA(const int* __restrict__ hist, int N,
                                             int* __restrict__ partial) {
    __shared__ int ts[256];
    int b = blockIdx.x, t = threadIdx.x;
    int i0 = b * 1024 + t * 4;
    int s = 0;
    #pragma unroll
    for (int q = 0; q < 4; ++q) s += (i0 + q < N) ? hist[i0 + q] : 0;
    ts[t] = s;
    __syncthreads();
    for (int off = 128; off; off >>= 1) {
        if (t < off) ts[t] += ts[t + off];
        __syncthreads();
    }
    if (t == 0) partial[b] = ts[0];
}

// parallel exclusive scan of up to 256 block partials
__global__ __launch_bounds__(256) void scanB(int* __restrict__ partial, int B1) {
    __shared__ int ts[256];
    int t = threadIdx.x;
    int v = (t < B1) ? partial[t] : 0;
    ts[t] = v;
    __syncthreads();
    for (int off = 1; off < 256; off <<= 1) {
        int x = (t >= off) ? ts[t - off] : 0;
        __syncthreads();
        ts[t] += x;
        __syncthreads();
    }
    if (t < B1) partial[t] = ts[t] - v;
}

__global__ __launch_bounds__(256) void scanC(const int* __restrict__ hist, int N,
                                             const int* __restrict__ partial,
                                             int* __restrict__ nodeStart,
                                             int* __restrict__ cursor) {
    __shared__ int ts[256];
    int b = blockIdx.x, t = threadIdx.x;
    int i0 = b * 1024 + t * 4;
    int v[4];
    int s = 0;
    #pragma unroll
    for (int q = 0; q < 4; ++q) { v[q] = (i0 + q < N) ? hist[i0 + q] : 0; s += v[q]; }
    ts[t] = s;
    __syncthreads();
    for (int off = 1; off < 256; off <<= 1) {
        int x = (t >= off) ? ts[t - off] : 0;
        __syncthreads();
        ts[t] += x;
        __syncthreads();
    }
    int run = partial[b] + ts[t] - s;
    #pragma unroll
    for (int q = 0; q < 4; ++q) {
        int i = i0 + q;
        if (i < N) {
            nodeStart[i] = run;
            cursor[i] = run;
            if (i == N - 1) nodeStart[N] = run + v[q];
            run += v[q];
        }
    }
}

// ---------------- relation kernels ----------------
template <int D, bool SORTED>
__global__ __launch_bounds__(256) void rel_mfma(
    const u16* __restrict__ statesb, const int* __restrict__ idx,
    const u16* __restrict__ W1t, const float* __restrict__ B1,
    const u16* __restrict__ W2t, const float* __restrict__ B2,
    float* __restrict__ exps, unsigned* __restrict__ gmax,
    int* __restrict__ cursor, _Float16* __restrict__ msgbuf, int E) {
    constexpr int A = D / 64;
    constexpr int NF = D / 16;
    constexpr int KF = D / 32;
    __shared__ __align__(16) u16 Xs[64 * D];
    __shared__ int Ids[64 * A];
    char* Xc = (char*)Xs;

    const int tid = threadIdx.x;
    const int block0 = blockIdx.x * 64;
    const int validRows = min(64, E - block0);
    const int validSegs = validRows * A;
    const long long segBase = (long long)block0 * A;

    for (int q = tid; q < 64 * A * 8; q += 256) {
        int s = q >> 3, j = q & 7;
        int r = s / A, slot = s - r * A;
        bf16x8 v = {};
        if (s < validSegs) {
            int node = idx[segBase + s];
            v = *reinterpret_cast<const bf16x8*>(statesb + (long long)node * 64 + j * 8);
            if (j == 0) Ids[s] = node;
        }
        int byte = (slot * 128 + j * 16) ^ ((r & 7) << 4);
        *reinterpret_cast<bf16x8*>(Xc + r * (2 * D) + byte) = v;
    }
    __syncthreads();

    const int l = tid & 63;
    const int ln = l & 15, kq = l >> 4;
    const int row0 = (tid >> 6) * 16;

    f32x4 acc[NF];
    #pragma unroll
    for (int n = 0; n < NF; ++n) {
        float b = B1[n * 16 + ln];
        acc[n] = {b, b, b, b};
    }
    {
        const u16* wb = W1t + ln * D + kq * 8;
        #pragma unroll
        for (int kf = 0; kf < KF; ++kf) {
            bf16x8 a = *reinterpret_cast<const bf16x8*>(
                Xc + (row0 + ln) * (2 * D) + ((kf * 64 + kq * 16) ^ ((ln & 7) << 4)));
            #pragma unroll
            for (int n = 0; n < NF; ++n) {
                bf16x8 b = *reinterpret_cast<const bf16x8*>(wb + n * 16 * D + kf * 32);
                acc[n] = __builtin_amdgcn_mfma_f32_16x16x32_bf16(a, b, acc[n], 0, 0, 0);
            }
        }
    }
    #pragma unroll
    for (int n = 0; n < NF; ++n) {
        #pragma unroll
        for (int j = 0; j < 4; ++j) {
            int rl = kq * 4 + j;
            int byte = ((n * 16 + ln) * 2) ^ ((rl & 7) << 4);
            *reinterpret_cast<u16*>(Xc + (row0 + rl) * (2 * D) + byte) =
                f2bf(fmaxf(acc[n][j], 0.f));
        }
    }
    #pragma unroll
    for (int n = 0; n < NF; ++n) {
        float b = B2[n * 16 + ln];
        acc[n] = {b, b, b, b};
    }
    {
        const u16* wb = W2t + ln * D + kq * 8;
        #pragma unroll
        for (int kf = 0; kf < KF; ++kf) {
            bf16x8 a = *reinterpret_cast<const bf16x8*>(
                Xc + (row0 + ln) * (2 * D) + ((kf * 64 + kq * 16) ^ ((ln & 7) << 4)));
            #pragma unroll
            for (int n = 0; n < NF; ++n) {
                bf16x8 b = *reinterpret_cast<const bf16x8*>(wb + n * 16 * D + kf * 32);
                acc[n] = __builtin_amdgcn_mfma_f32_16x16x32_bf16(a, b, acc[n], 0, 0, 0);
            }
        }
    }

    float m = -INFINITY;
    #pragma unroll
    for (int n = 0; n < NF; ++n)
        #pragma unroll
        for (int j = 0; j < 4; ++j) {
            int row = row0 + kq * 4 + j;
            if (row < validRows) m = fmaxf(m, acc[n][j]);
        }
    #pragma unroll
    for (int off = 32; off; off >>= 1) m = fmaxf(m, __shfl_xor(m, off));
    if (l == 0) atomicMax(gmax, f2ord(m));

    if constexpr (SORTED) {
        #pragma unroll
        for (int j = 0; j < 4; ++j) {
            int row = row0 + kq * 4 + j;
            bool valid = row < validRows;
            int pos[A];
            #pragma unroll
            for (int s = 0; s < A; ++s) {
                int p = 0;
                if (ln == s && valid) {
                    int node = Ids[row * A + s];
                    p = atomicAdd(&cursor[node], 1);
                }
                pos[s] = __shfl(p, kq * 16 + s);
            }
            if (valid) {
                #pragma unroll
                for (int n = 0; n < NF; ++n) {
                    int slot = n >> 2;
                    int feat = (n & 3) * 16 + ln;
                    msgbuf[(long long)pos[slot] * 64 + feat] =
                        (_Float16)__expf(8.f * acc[n][j]);
                }
            }
        }
    } else {
        #pragma unroll
        for (int n = 0; n < NF; ++n) {
            const int slot = n >> 2;
            const int feat = (n * 16 + ln) & 63;
            #pragma unroll
            for (int j = 0; j < 4; ++j) {
                int row = row0 + kq * 4 + j;
                if (row < validRows) {
                    int node = Ids[row * A + slot];
                    atomicAdd(exps + (long long)node * 64 + feat, __expf(8.f * acc[n][j]));
                }
            }
        }
    }
}

// ---------------- segment reduce (accumulating, per chunk) ----------------
__global__ __launch_bounds__(256) void reduce_accum(const _Float16* __restrict__ msgbuf,
                                                    const int* __restrict__ nodeStart,
                                                    float* __restrict__ exps, int Nn) {
    int node = (blockIdx.x * 256 + threadIdx.x) >> 6;
    if (node >= Nn) return;
    int lane = threadIdx.x & 63;
    int s = nodeStart[node], e = nodeStart[node + 1];
    if (s == e) return;
    float S = 0.f;
    for (int i = s; i < e; ++i) S += (float)msgbuf[(long long)i * 64 + lane];
    exps[(long long)node * 64 + lane] += S;
}

// ---------------- up kernel ----------------
__global__ __launch_bounds__(256) void up_mfma(
    const u16* __restrict__ statesb, const float* __restrict__ exps,
    const unsigned* __restrict__ gmaxp,
    const u16* __restrict__ W1t, const float* __restrict__ B1,
    const u16* __restrict__ W2t, const float* __restrict__ B2,
    float* __restrict__ outp, int Nn) {
    constexpr int D = 128;
    __shared__ __align__(16) u16 Xs[64 * D];
    char* Xc = (char*)Xs;
    const int tid = threadIdx.x;
    const int block0 = blockIdx.x * 64;
    const int validRows = min(64, Nn - block0);
    const float M = ord2f(*gmaxp);
    const float EM = __expf(-8.f * M);

    for (int q = tid; q < 64 * 16; q += 256) {
        int r = q >> 4, p = q & 15;
        bf16x8 v = {};
        if (r < validRows) {
            long long nd = block0 + r;
            if (p < 8) {
                float4 s0 = *reinterpret_cast<const float4*>(exps + nd * 64 + p * 8);
                float4 s1 = *reinterpret_cast<const float4*>(exps + nd * 64 + p * 8 + 4);
                float t[8] = {s0.x, s0.y, s0.z, s0.w, s1.x, s1.y, s1.z, s1.w};
                #pragma unroll
                for (int i = 0; i < 8; ++i)
                    v[i] = (short)f2bf(__logf(1e-16f + t[i] * EM) * 0.125f + M);
            } else {
                v = *reinterpret_cast<const bf16x8*>(statesb + nd * 64 + (p - 8) * 8);
            }
        }
        int byte = (p * 16) ^ ((r & 7) << 4);
        *reinterpret_cast<bf16x8*>(Xc + r * 256 + byte) = v;
    }
    __syncthreads();

    const int l = tid & 63;
    const int ln = l & 15, kq = l >> 4;
    const int row0 = (tid >> 6) * 16;

    f32x4 acc[8];
    #pragma unroll
    for (int n = 0; n < 8; ++n) {
        float b = B1[n * 16 + ln];
        acc[n] = {b, b, b, b};
    }
    {
        const u16* wb = W1t + ln * D + kq * 8;
        #pragma unroll
        for (int kf = 0; kf < 4; ++kf) {
            bf16x8 a = *reinterpret_cast<const bf16x8*>(
                Xc + (row0 + ln) * 256 + ((kf * 64 + kq * 16) ^ ((ln & 7) << 4)));
            #pragma unroll
            for (int n = 0; n < 8; ++n) {
                bf16x8 b = *reinterpret_cast<const bf16x8*>(wb + n * 16 * D + kf * 32);
                acc[n] = __builtin_amdgcn_mfma_f32_16x16x32_bf16(a, b, acc[n], 0, 0, 0);
            }
        }
    }
    #pragma unroll
    for (int n = 0; n < 8; ++n) {
        #pragma unroll
        for (int j = 0; j < 4; ++j) {
            int rl = kq * 4 + j;
            int byte = ((n * 16 + ln) * 2) ^ ((rl & 7) << 4);
            *reinterpret_cast<u16*>(Xc + (row0 + rl) * 256 + byte) =
                f2bf(fmaxf(acc[n][j], 0.f));
        }
    }
    f32x4 acc2[4];
    #pragma unroll
    for (int n = 0; n < 4; ++n) {
        float b = B2[n * 16 + ln];
        acc2[n] = {b, b, b, b};
    }
    {
        const u16* wb = W2t + ln * D + kq * 8;
        #pragma unroll
        for (int kf = 0; kf < 4; ++kf) {
            bf16x8 a = *reinterpret_cast<const bf16x8*>(
                Xc + (row0 + ln) * 256 + ((kf * 64 + kq * 16) ^ ((ln & 7) << 4)));
            #pragma unroll
            for (int n = 0; n < 4; ++n) {
                bf16x8 b = *reinterpret_cast<const bf16x8*>(wb + n * 16 * D + kf * 32);
                acc2[n] = __builtin_amdgcn_mfma_f32_16x16x32_bf16(a, b, acc2[n], 0, 0, 0);
            }
        }
    }
    #pragma unroll
    for (int n = 0; n < 4; ++n)
        #pragma unroll
        for (int j = 0; j < 4; ++j) {
            int row = row0 + kq * 4 + j;
            if (row < validRows)
                outp[(long long)(block0 + row) * 64 + n * 16 + ln] = acc2[n][j];
        }
}

extern "C" void kernel_launch(void* const* d_in, const int* in_sizes, int n_in,
                              void* d_out, int out_size, void* d_ws, size_t ws_size,
                              hipStream_t stream) {
    const float* states = (const float*)d_in[0];
    const int* idxp[3] = {(const int*)d_in[1], (const int*)d_in[2], (const int*)d_in[3]};
    const float* rw1[3] = {(const float*)d_in[4], (const float*)d_in[8], (const float*)d_in[12]};
    const float* rb1[3] = {(const float*)d_in[5], (const float*)d_in[9], (const float*)d_in[13]};
    const float* rw2[3] = {(const float*)d_in[6], (const float*)d_in[10], (const float*)d_in[14]};
    const float* rb2[3] = {(const float*)d_in[7], (const float*)d_in[11], (const float*)d_in[15]};
    const float* upw1 = (const float*)d_in[16];
    const float* upb1 = (const float*)d_in[17];
    const float* upw2 = (const float*)d_in[18];
    const float* upb2 = (const float*)d_in[19];

    const int N = in_sizes[0] / 64;
    const int Lr[3] = {in_sizes[1], in_sizes[2], in_sizes[3]};
    const int Ar[3] = {1, 2, 3};
    const int Er[3] = {Lr[0] / 1, Lr[1] / 2, Lr[2] / 3};
    const int Dd[3] = {64, 128, 192};

    size_t off = 0;
    auto alloc = [&](size_t bytes) {
        void* p = (char*)d_ws + off;
        off += (bytes + 255) & ~(size_t)255;
        return p;
    };
    unsigned* gmax = (unsigned*)alloc(4);
    int* hist = (int*)alloc((size_t)N * 4);
    int* nodeStart = (int*)alloc((size_t)(N + 1) * 4);
    int* partial = (int*)alloc(4096);
    int* cursor = (int*)alloc((size_t)N * 4);
    float* exps = (float*)alloc((size_t)N * 64 * 4);
    size_t zero_end = off;                       // memset range: gmax..exps
    u16* statesb = (u16*)alloc((size_t)N * 64 * 2);
    u16* w1t[3], *w2t[3];
    for (int r = 0; r < 3; ++r) {
        w1t[r] = (u16*)alloc((size_t)Dd[r] * Dd[r] * 2);
        w2t[r] = (u16*)alloc((size_t)Dd[r] * Dd[r] * 2);
    }
    u16* upw1t = (u16*)alloc(128 * 128 * 2);
    u16* upw2t = (u16*)alloc(64 * 128 * 2);
    _Float16* msgbuf = (_Float16*)((char*)d_ws + off);

    // msgbuf capacity in participants; chunks per relation
    long long capParts = (ws_size > off) ? (long long)((ws_size - off) / 128) : 0;
    int tc[3], nch[3], totalChunks = 0;
    bool sorted = capParts >= 4096 && N <= 256 * 1024;
    if (sorted) {
        for (int r = 0; r < 3; ++r) {
            long long capT = capParts / Ar[r];
            tc[r] = (int)(capT < Er[r] ? capT : Er[r]);
            nch[r] = (Er[r] + tc[r] - 1) / tc[r];
            totalChunks += nch[r];
        }
        sorted = totalChunks <= 16;
    }

    TPack tp;
    const float* tsrc[8] = {rw1[0], rw2[0], rw1[1], rw2[1], rw1[2], rw2[2], upw1, upw2};
    const int tK[8] = {64, 64, 128, 128, 192, 192, 128, 128};
    const int tN[8] = {64, 64, 128, 128, 192, 192, 128, 64};
    const int B1n = (N + 1023) / 1024;

    if (sorted) {
        hipMemsetAsync(d_ws, 0, zero_end, stream);   // gmax+hist+scan bufs+exps
        conv_states<<<dim3((N * 64 / 8 + 255) / 256), dim3(256), 0, stream>>>(
            states, statesb, N * 64 / 8);
        u16* tdst[8] = {w1t[0], w2t[0], w1t[1], w2t[1], w1t[2], w2t[2], upw1t, upw2t};
        int base = 0;
        for (int i = 0; i < 8; ++i) {
            tp.e[i] = {tsrc[i], tdst[i], tK[i], tN[i], base};
            base += (tK[i] * tN[i] + 255) / 256;
        }
        transpose_w<<<dim3(base), dim3(256), 0, stream>>>(tp);

        bool firstChunk = true;
        for (int r = 0; r < 3; ++r) {
            for (int c = 0; c < nch[r]; ++c) {
                int t0 = c * tc[r];
                int tcnt = Er[r] - t0 < tc[r] ? Er[r] - t0 : tc[r];
                const int* idxc = idxp[r] + (long long)t0 * Ar[r];
                int parts = tcnt * Ar[r];
                if (!firstChunk)
                    hipMemsetAsync(hist, 0, (size_t)N * 4, stream);
                firstChunk = false;
                hist_k<<<dim3((parts + 255) / 256), dim3(256), 0, stream>>>(idxc, parts, hist);
                scanA<<<dim3(B1n), dim3(256), 0, stream>>>(hist, N, partial);
                scanB<<<dim3(1), dim3(256), 0, stream>>>(partial, B1n);
                scanC<<<dim3(B1n), dim3(256), 0, stream>>>(hist, N, partial, nodeStart, cursor);
                if (r == 0)
                    rel_mfma<64, true><<<dim3((tcnt + 63) / 64), dim3(256), 0, stream>>>(
                        statesb, idxc, w1t[0], rb1[0], w2t[0], rb2[0], nullptr, gmax, cursor, msgbuf, tcnt);
                else if (r == 1)
                    rel_mfma<128, true><<<dim3((tcnt + 63) / 64), dim3(256), 0, stream>>>(
                        statesb, idxc, w1t[1], rb1[1], w2t[1], rb2[1], nullptr, gmax, cursor, msgbuf, tcnt);
                else
                    rel_mfma<192, true><<<dim3((tcnt + 63) / 64), dim3(256), 0, stream>>>(
                        statesb, idxc, w1t[2], rb1[2], w2t[2], rb2[2], nullptr, gmax, cursor, msgbuf, tcnt);
                reduce_accum<<<dim3((N * 64 + 255) / 256), dim3(256), 0, stream>>>(
                    msgbuf, nodeStart, exps, N);
            }
        }
        up_mfma<<<dim3((N + 63) / 64), dim3(256), 0, stream>>>(
            statesb, exps, gmax, upw1t, upb1, upw2t, upb2, (float*)d_out, N);
    } else {
        // ---- fallback: round-3 atomic path
        off = 0;
        unsigned* g2 = (unsigned*)alloc(4);
        float* ex2 = (float*)alloc((size_t)N * 64 * 4);
        u16* sb2 = (u16*)alloc((size_t)N * 64 * 2);
        u16* fw1[3], *fw2[3];
        for (int r = 0; r < 3; ++r) {
            fw1[r] = (u16*)alloc((size_t)Dd[r] * Dd[r] * 2);
            fw2[r] = (u16*)alloc((size_t)Dd[r] * Dd[r] * 2);
        }
        u16* uw1 = (u16*)alloc(128 * 128 * 2);
        u16* uw2 = (u16*)alloc(64 * 128 * 2);
        hipMemsetAsync(d_ws, 0, 256 + (size_t)N * 64 * 4, stream);
        conv_states<<<dim3((N * 64 / 8 + 255) / 256), dim3(256), 0, stream>>>(
            states, sb2, N * 64 / 8);
        u16* tdst[8] = {fw1[0], fw2[0], fw1[1], fw2[1], fw1[2], fw2[2], uw1, uw2};
        int base = 0;
        for (int i = 0; i < 8; ++i) {
            tp.e[i] = {tsrc[i], tdst[i], tK[i], tN[i], base};
            base += (tK[i] * tN[i] + 255) / 256;
        }
        transpose_w<<<dim3(base), dim3(256), 0, stream>>>(tp);
        rel_mfma<64, false><<<dim3((Er[0] + 63) / 64), dim3(256), 0, stream>>>(
            sb2, idxp[0], fw1[0], rb1[0], fw2[0], rb2[0], ex2, g2, nullptr, nullptr, Er[0]);
        rel_mfma<128, false><<<dim3((Er[1] + 63) / 64), dim3(256), 0, stream>>>(
            sb2, idxp[1], fw1[1], rb1[1], fw2[1], rb2[1], ex2, g2, nullptr, nullptr, Er[1]);
        rel_mfma<192, false><<<dim3((Er[2] + 63) / 64), dim3(256), 0, stream>>>(
            sb2, idxp[2], fw1[2], rb1[2], fw2[2], rb2[2], ex2, g2, nullptr, nullptr, Er[2]);
        up_mfma<<<dim3((N + 63) / 64), dim3(256), 0, stream>>>(
            sb2, ex2, g2, uw1, upb1, uw2, upb2, (float*)d_out, N);
    }
}

// Round 6
// 752.549 us; speedup vs baseline: 1.8647x; 1.8647x over previous
//
#include <hip/hip_runtime.h>
#include <math.h>

// RelationMessagePassing — bf16 MFMA, atomic exps scatter, NO hot-line atomic.
//
// Round-5 finding: rel-kernel time tracks WAVE COUNT, not D, not scatter style
// (atomic vs CSR identical). Suspect: per-wave atomicMax(gmax) — one global
// cache line RMW'd by 68.8k waves, serialized device-wide (~13ns/op ≈ 0.9ms),
// and waves can't retire until vmcnt drains => occupancy convoy.
// Fix: per-block LDS max reduce -> PLAIN store to blockmax[bid] -> tiny
// reduce_max kernel -> float gmax. Zero same-address atomics in hot kernels.
//
// Also: fold 8x into W2/B2 (transpose-time scale) => epilogue exp(acc) direct;
// blockmax stores max(acc)/8 to recover the o-scale max.
//
// Pipeline: memset exps | conv_states | transpose_w(scaled) |
//   rel_mfma<64/128/192>: gather->MFMA MLP->blockmax store + atomicAdd exp ->
//   reduce_max | up_mfma (max_msg=log(1e-16+S*e^-8M)/8+M; concat; MLP; fp32 out)

typedef __attribute__((ext_vector_type(8))) short bf16x8;
typedef __attribute__((ext_vector_type(4))) float f32x4;
typedef unsigned short u16;

__device__ __forceinline__ u16 f2bf(float f) {   // RNE f32->bf16 (finite)
    unsigned u = __float_as_uint(f);
    return (u16)((u + 0x7fffu + ((u >> 16) & 1u)) >> 16);
}

// ---------------- prep ----------------
__global__ __launch_bounds__(256) void conv_states(const float* __restrict__ src,
                                                   u16* __restrict__ dst, int n8) {
    int i = blockIdx.x * 256 + threadIdx.x;
    if (i >= n8) return;
    float4 a = reinterpret_cast<const float4*>(src)[2 * i];
    float4 b = reinterpret_cast<const float4*>(src)[2 * i + 1];
    bf16x8 v;
    v[0] = (short)f2bf(a.x); v[1] = (short)f2bf(a.y);
    v[2] = (short)f2bf(a.z); v[3] = (short)f2bf(a.w);
    v[4] = (short)f2bf(b.x); v[5] = (short)f2bf(b.y);
    v[6] = (short)f2bf(b.z); v[7] = (short)f2bf(b.w);
    reinterpret_cast<bf16x8*>(dst)[i] = v;
}

struct TEnt { const float* src; u16* dst; int K, N, base; float scale; };
struct TPack { TEnt e[8]; };
// dst[n*K + k] = bf16(scale * src[k*N + n])
__global__ __launch_bounds__(256) void transpose_w(TPack p) {
    int b = blockIdx.x;
    int i = 0;
    while (i < 7 && b >= p.e[i + 1].base) ++i;
    TEnt e = p.e[i];
    int idx = (b - e.base) * 256 + threadIdx.x;
    if (idx < e.K * e.N) {
        int n = idx / e.K, k = idx - n * e.K;
        e.dst[idx] = f2bf(e.scale * e.src[k * e.N + n]);
    }
}

// ---------------- relation kernels ----------------
// D = arity*64; one block = 64 tuples, 4 waves x 16 rows.
// Layer2 weights/bias pre-scaled by 8 => acc' = 8*o; store exp(acc'),
// blockmax = max(acc')/8.
template <int D>
__global__ __launch_bounds__(256) void rel_mfma(
    const u16* __restrict__ statesb, const int* __restrict__ idx,
    const u16* __restrict__ W1t, const float* __restrict__ B1,
    const u16* __restrict__ W2t, const float* __restrict__ B2,
    float* __restrict__ exps, float* __restrict__ blockmax, int E) {
    constexpr int A = D / 64;
    constexpr int NF = D / 16;
    constexpr int KF = D / 32;
    __shared__ __align__(16) u16 Xs[64 * D];
    __shared__ int Ids[64 * A];
    __shared__ float wmax[4];
    char* Xc = (char*)Xs;

    const int tid = threadIdx.x;
    const int block0 = blockIdx.x * 64;
    const int validRows = min(64, E - block0);
    const int validSegs = validRows * A;
    const long long segBase = (long long)block0 * A;

    // gather: seg s -> row s/A, col-block (s%A); XOR-swizzled LDS rows
    for (int q = tid; q < 64 * A * 8; q += 256) {
        int s = q >> 3, j = q & 7;
        int r = s / A, slot = s - r * A;
        bf16x8 v = {};
        if (s < validSegs) {
            int node = idx[segBase + s];
            v = *reinterpret_cast<const bf16x8*>(statesb + (long long)node * 64 + j * 8);
            if (j == 0) Ids[s] = node;
        }
        int byte = (slot * 128 + j * 16) ^ ((r & 7) << 4);
        *reinterpret_cast<bf16x8*>(Xc + r * (2 * D) + byte) = v;
    }
    __syncthreads();

    const int l = tid & 63;
    const int ln = l & 15, kq = l >> 4;
    const int row0 = (tid >> 6) * 16;

    f32x4 acc[NF];
    // ---- layer 1: h = relu(x@W1 + b1)
    #pragma unroll
    for (int n = 0; n < NF; ++n) {
        float b = B1[n * 16 + ln];
        acc[n] = {b, b, b, b};
    }
    {
        const u16* wb = W1t + ln * D + kq * 8;
        #pragma unroll
        for (int kf = 0; kf < KF; ++kf) {
            bf16x8 a = *reinterpret_cast<const bf16x8*>(
                Xc + (row0 + ln) * (2 * D) + ((kf * 64 + kq * 16) ^ ((ln & 7) << 4)));
            #pragma unroll
            for (int n = 0; n < NF; ++n) {
                bf16x8 b = *reinterpret_cast<const bf16x8*>(wb + n * 16 * D + kf * 32);
                acc[n] = __builtin_amdgcn_mfma_f32_16x16x32_bf16(a, b, acc[n], 0, 0, 0);
            }
        }
    }
    // relu -> H into this wave's own rows (wave-local, no barrier)
    #pragma unroll
    for (int n = 0; n < NF; ++n) {
        #pragma unroll
        for (int j = 0; j < 4; ++j) {
            int rl = kq * 4 + j;
            int byte = ((n * 16 + ln) * 2) ^ ((rl & 7) << 4);
            *reinterpret_cast<u16*>(Xc + (row0 + rl) * (2 * D) + byte) =
                f2bf(fmaxf(acc[n][j], 0.f));
        }
    }
    // ---- layer 2 (pre-scaled): acc' = 8*(h@W2 + b2)
    #pragma unroll
    for (int n = 0; n < NF; ++n) {
        float b = 8.f * B2[n * 16 + ln];
        acc[n] = {b, b, b, b};
    }
    {
        const u16* wb = W2t + ln * D + kq * 8;
        #pragma unroll
        for (int kf = 0; kf < KF; ++kf) {
            bf16x8 a = *reinterpret_cast<const bf16x8*>(
                Xc + (row0 + ln) * (2 * D) + ((kf * 64 + kq * 16) ^ ((ln & 7) << 4)));
            #pragma unroll
            for (int n = 0; n < NF; ++n) {
                bf16x8 b = *reinterpret_cast<const bf16x8*>(wb + n * 16 * D + kf * 32);
                acc[n] = __builtin_amdgcn_mfma_f32_16x16x32_bf16(a, b, acc[n], 0, 0, 0);
            }
        }
    }

    // ---- epilogue: block max (plain store) + exp scatter (spread atomics)
    float m = -INFINITY;
    #pragma unroll
    for (int n = 0; n < NF; ++n)
        #pragma unroll
        for (int j = 0; j < 4; ++j) {
            int row = row0 + kq * 4 + j;
            if (row < validRows) m = fmaxf(m, acc[n][j]);
        }
    #pragma unroll
    for (int off = 32; off; off >>= 1) m = fmaxf(m, __shfl_xor(m, off));
    if (l == 0) wmax[tid >> 6] = m;
    __syncthreads();
    if (tid == 0)
        blockmax[blockIdx.x] =
            0.125f * fmaxf(fmaxf(wmax[0], wmax[1]), fmaxf(wmax[2], wmax[3]));

    #pragma unroll
    for (int n = 0; n < NF; ++n) {
        const int slot = n >> 2;
        const int feat = (n * 16 + ln) & 63;
        #pragma unroll
        for (int j = 0; j < 4; ++j) {
            int row = row0 + kq * 4 + j;
            if (row < validRows) {
                int node = Ids[row * A + slot];
                atomicAdd(exps + (long long)node * 64 + feat, __expf(acc[n][j]));
            }
        }
    }
}

// ---------------- global max over block maxima ----------------
__global__ __launch_bounds__(256) void reduce_max(const float* __restrict__ bm,
                                                  int n, float* __restrict__ out) {
    __shared__ float ws_[4];
    float m = -INFINITY;
    for (int i = threadIdx.x; i < n; i += 256) m = fmaxf(m, bm[i]);
    #pragma unroll
    for (int off = 32; off; off >>= 1) m = fmaxf(m, __shfl_xor(m, off));
    if ((threadIdx.x & 63) == 0) ws_[threadIdx.x >> 6] = m;
    __syncthreads();
    if (threadIdx.x == 0)
        out[0] = fmaxf(fmaxf(ws_[0], ws_[1]), fmaxf(ws_[2], ws_[3]));
}

// ---------------- up kernel ----------------
__global__ __launch_bounds__(256) void up_mfma(
    const u16* __restrict__ statesb, const float* __restrict__ exps,
    const float* __restrict__ gmaxp,
    const u16* __restrict__ W1t, const float* __restrict__ B1,
    const u16* __restrict__ W2t, const float* __restrict__ B2,
    float* __restrict__ outp, int Nn) {
    constexpr int D = 128;
    __shared__ __align__(16) u16 Xs[64 * D];
    char* Xc = (char*)Xs;
    const int tid = threadIdx.x;
    const int block0 = blockIdx.x * 64;
    const int validRows = min(64, Nn - block0);
    const float M = gmaxp[0];
    const float EM = __expf(-8.f * M);

    // X tile: cols 0..63 = max_msg, 64..127 = states
    for (int q = tid; q < 64 * 16; q += 256) {
        int r = q >> 4, p = q & 15;
        bf16x8 v = {};
        if (r < validRows) {
            long long nd = block0 + r;
            if (p < 8) {
                float4 s0 = *reinterpret_cast<const float4*>(exps + nd * 64 + p * 8);
                float4 s1 = *reinterpret_cast<const float4*>(exps + nd * 64 + p * 8 + 4);
                float t[8] = {s0.x, s0.y, s0.z, s0.w, s1.x, s1.y, s1.z, s1.w};
                #pragma unroll
                for (int i = 0; i < 8; ++i)
                    v[i] = (short)f2bf(__logf(1e-16f + t[i] * EM) * 0.125f + M);
            } else {
                v = *reinterpret_cast<const bf16x8*>(statesb + nd * 64 + (p - 8) * 8);
            }
        }
        int byte = (p * 16) ^ ((r & 7) << 4);
        *reinterpret_cast<bf16x8*>(Xc + r * 256 + byte) = v;
    }
    __syncthreads();

    const int l = tid & 63;
    const int ln = l & 15, kq = l >> 4;
    const int row0 = (tid >> 6) * 16;

    f32x4 acc[8];
    #pragma unroll
    for (int n = 0; n < 8; ++n) {
        float b = B1[n * 16 + ln];
        acc[n] = {b, b, b, b};
    }
    {
        const u16* wb = W1t + ln * D + kq * 8;
        #pragma unroll
        for (int kf = 0; kf < 4; ++kf) {
            bf16x8 a = *reinterpret_cast<const bf16x8*>(
                Xc + (row0 + ln) * 256 + ((kf * 64 + kq * 16) ^ ((ln & 7) << 4)));
            #pragma unroll
            for (int n = 0; n < 8; ++n) {
                bf16x8 b = *reinterpret_cast<const bf16x8*>(wb + n * 16 * D + kf * 32);
                acc[n] = __builtin_amdgcn_mfma_f32_16x16x32_bf16(a, b, acc[n], 0, 0, 0);
            }
        }
    }
    #pragma unroll
    for (int n = 0; n < 8; ++n) {
        #pragma unroll
        for (int j = 0; j < 4; ++j) {
            int rl = kq * 4 + j;
            int byte = ((n * 16 + ln) * 2) ^ ((rl & 7) << 4);
            *reinterpret_cast<u16*>(Xc + (row0 + rl) * 256 + byte) =
                f2bf(fmaxf(acc[n][j], 0.f));
        }
    }
    f32x4 acc2[4];
    #pragma unroll
    for (int n = 0; n < 4; ++n) {
        float b = B2[n * 16 + ln];
        acc2[n] = {b, b, b, b};
    }
    {
        const u16* wb = W2t + ln * D + kq * 8;   // W2t is [64][128]
        #pragma unroll
        for (int kf = 0; kf < 4; ++kf) {
            bf16x8 a = *reinterpret_cast<const bf16x8*>(
                Xc + (row0 + ln) * 256 + ((kf * 64 + kq * 16) ^ ((ln & 7) << 4)));
            #pragma unroll
            for (int n = 0; n < 4; ++n) {
                bf16x8 b = *reinterpret_cast<const bf16x8*>(wb + n * 16 * D + kf * 32);
                acc2[n] = __builtin_amdgcn_mfma_f32_16x16x32_bf16(a, b, acc2[n], 0, 0, 0);
            }
        }
    }
    #pragma unroll
    for (int n = 0; n < 4; ++n)
        #pragma unroll
        for (int j = 0; j < 4; ++j) {
            int row = row0 + kq * 4 + j;
            if (row < validRows)
                outp[(long long)(block0 + row) * 64 + n * 16 + ln] = acc2[n][j];
        }
}

extern "C" void kernel_launch(void* const* d_in, const int* in_sizes, int n_in,
                              void* d_out, int out_size, void* d_ws, size_t ws_size,
                              hipStream_t stream) {
    const float* states = (const float*)d_in[0];
    const int* idxp[3] = {(const int*)d_in[1], (const int*)d_in[2], (const int*)d_in[3]};
    const float* rw1[3] = {(const float*)d_in[4], (const float*)d_in[8], (const float*)d_in[12]};
    const float* rb1[3] = {(const float*)d_in[5], (const float*)d_in[9], (const float*)d_in[13]};
    const float* rw2[3] = {(const float*)d_in[6], (const float*)d_in[10], (const float*)d_in[14]};
    const float* rb2[3] = {(const float*)d_in[7], (const float*)d_in[11], (const float*)d_in[15]};
    const float* upw1 = (const float*)d_in[16];
    const float* upb1 = (const float*)d_in[17];
    const float* upw2 = (const float*)d_in[18];
    const float* upb2 = (const float*)d_in[19];

    const int N = in_sizes[0] / 64;
    const int E0 = in_sizes[1] / 1;
    const int E1 = in_sizes[2] / 2;
    const int E2 = in_sizes[3] / 3;
    const int G0 = (E0 + 63) / 64, G1 = (E1 + 63) / 64, G2 = (E2 + 63) / 64;
    const int Gtot = G0 + G1 + G2;
    const int Dd[3] = {64, 128, 192};

    size_t off = 0;
    auto alloc = [&](size_t bytes) {
        void* p = (char*)d_ws + off;
        off += (bytes + 255) & ~(size_t)255;
        return p;
    };
    float* gmaxf = (float*)alloc(4);
    float* blockmax = (float*)alloc((size_t)Gtot * 4);
    float* exps = (float*)alloc((size_t)N * 64 * 4);
    u16* statesb = (u16*)alloc((size_t)N * 64 * 2);
    u16* w1t[3], *w2t[3];
    for (int r = 0; r < 3; ++r) {
        w1t[r] = (u16*)alloc((size_t)Dd[r] * Dd[r] * 2);
        w2t[r] = (u16*)alloc((size_t)Dd[r] * Dd[r] * 2);
    }
    u16* upw1t = (u16*)alloc(128 * 128 * 2);
    u16* upw2t = (u16*)alloc(64 * 128 * 2);

    // zero exps only (gmaxf/blockmax fully overwritten every launch)
    hipMemsetAsync(exps, 0, (size_t)N * 64 * 4, stream);

    conv_states<<<dim3((N * 64 / 8 + 255) / 256), dim3(256), 0, stream>>>(
        states, statesb, N * 64 / 8);

    TPack tp;
    const float* tsrc[8] = {rw1[0], rw2[0], rw1[1], rw2[1], rw1[2], rw2[2], upw1, upw2};
    u16* tdst[8] = {w1t[0], w2t[0], w1t[1], w2t[1], w1t[2], w2t[2], upw1t, upw2t};
    const int tK[8] = {64, 64, 128, 128, 192, 192, 128, 128};
    const int tN[8] = {64, 64, 128, 128, 192, 192, 128, 64};
    const float tsc[8] = {1.f, 8.f, 1.f, 8.f, 1.f, 8.f, 1.f, 1.f};
    int base = 0;
    for (int i = 0; i < 8; ++i) {
        tp.e[i] = {tsrc[i], tdst[i], tK[i], tN[i], base, tsc[i]};
        base += (tK[i] * tN[i] + 255) / 256;
    }
    transpose_w<<<dim3(base), dim3(256), 0, stream>>>(tp);

    rel_mfma<64><<<dim3(G0), dim3(256), 0, stream>>>(
        statesb, idxp[0], w1t[0], rb1[0], w2t[0], rb2[0], exps, blockmax, E0);
    rel_mfma<128><<<dim3(G1), dim3(256), 0, stream>>>(
        statesb, idxp[1], w1t[1], rb1[1], w2t[1], rb2[1], exps, blockmax + G0, E1);
    rel_mfma<192><<<dim3(G2), dim3(256), 0, stream>>>(
        statesb, idxp[2], w1t[2], rb1[2], w2t[2], rb2[2], exps, blockmax + G0 + G1, E2);

    reduce_max<<<dim3(1), dim3(256), 0, stream>>>(blockmax, Gtot, gmaxf);

    up_mfma<<<dim3((N + 63) / 64), dim3(256), 0, stream>>>(
        statesb, exps, gmaxf, upw1t, upb1, upw2t, upb2, (float*)d_out, N);
}

// Round 7
// 751.997 us; speedup vs baseline: 1.8660x; 1.0007x over previous
//
#include <hip/hip_runtime.h>
#include <hip/hip_fp16.h>
#include <math.h>

// RelationMessagePassing — bf16 MFMA + packed-fp16 atomic scatter.
//
// Round-6 finding: rel kernels sit at ~116 G fp32-atomic-RMW/s (device-scope
// atomics resolve below the 8 non-coherent L2s); WRITE_SIZE == atomic bytes.
// This round halves RMW ops via global_atomic_pk_add_f16: shfl_xor(1) pairs
// adjacent feats (adjacent lanes in MFMA C layout) -> even lanes issue one
// 2xfp16 packed atomic each. exps becomes fp16[N*64]; up-MLP attenuates the
// added fp16-accumulation error (~0.2 gain), so output impact ~1e-4.
//
// Pipeline: memset exps | conv_states | transpose_w (W2 pre-scaled by 8) |
//   rel_mfma<64/128/192>: gather -> MFMA MLP -> blockmax store +
//     pk_f16 atomicAdd exp(acc') -> reduce_max |
//   up_mfma: max_msg = log(1e-16 + S*e^-8M)/8 + M; concat; MFMA; fp32 out.

typedef __attribute__((ext_vector_type(8))) short bf16x8;
typedef __attribute__((ext_vector_type(4))) float f32x4;
typedef unsigned short u16;

__device__ __forceinline__ u16 f2bf(float f) {   // RNE f32->bf16 (finite)
    unsigned u = __float_as_uint(f);
    return (u16)((u + 0x7fffu + ((u >> 16) & 1u)) >> 16);
}

// ---------------- prep ----------------
__global__ __launch_bounds__(256) void conv_states(const float* __restrict__ src,
                                                   u16* __restrict__ dst, int n8) {
    int i = blockIdx.x * 256 + threadIdx.x;
    if (i >= n8) return;
    float4 a = reinterpret_cast<const float4*>(src)[2 * i];
    float4 b = reinterpret_cast<const float4*>(src)[2 * i + 1];
    bf16x8 v;
    v[0] = (short)f2bf(a.x); v[1] = (short)f2bf(a.y);
    v[2] = (short)f2bf(a.z); v[3] = (short)f2bf(a.w);
    v[4] = (short)f2bf(b.x); v[5] = (short)f2bf(b.y);
    v[6] = (short)f2bf(b.z); v[7] = (short)f2bf(b.w);
    reinterpret_cast<bf16x8*>(dst)[i] = v;
}

struct TEnt { const float* src; u16* dst; int K, N, base; float scale; };
struct TPack { TEnt e[8]; };
// dst[n*K + k] = bf16(scale * src[k*N + n])
__global__ __launch_bounds__(256) void transpose_w(TPack p) {
    int b = blockIdx.x;
    int i = 0;
    while (i < 7 && b >= p.e[i + 1].base) ++i;
    TEnt e = p.e[i];
    int idx = (b - e.base) * 256 + threadIdx.x;
    if (idx < e.K * e.N) {
        int n = idx / e.K, k = idx - n * e.K;
        e.dst[idx] = f2bf(e.scale * e.src[k * e.N + n]);
    }
}

// ---------------- relation kernels ----------------
// D = arity*64; one block = 64 tuples, 4 waves x 16 rows.
// Layer2 pre-scaled by 8 => acc' = 8*o; scatter exp(acc'), blockmax = max/8.
template <int D>
__global__ __launch_bounds__(256) void rel_mfma(
    const u16* __restrict__ statesb, const int* __restrict__ idx,
    const u16* __restrict__ W1t, const float* __restrict__ B1,
    const u16* __restrict__ W2t, const float* __restrict__ B2,
    __half* __restrict__ exps, float* __restrict__ blockmax, int E) {
    constexpr int A = D / 64;
    constexpr int NF = D / 16;
    constexpr int KF = D / 32;
    __shared__ __align__(16) u16 Xs[64 * D];
    __shared__ int Ids[64 * A];
    __shared__ float wmax[4];
    char* Xc = (char*)Xs;

    const int tid = threadIdx.x;
    const int block0 = blockIdx.x * 64;
    const int validRows = min(64, E - block0);
    const int validSegs = validRows * A;
    const long long segBase = (long long)block0 * A;

    // gather: seg s -> row s/A, col-block (s%A); XOR-swizzled LDS rows
    for (int q = tid; q < 64 * A * 8; q += 256) {
        int s = q >> 3, j = q & 7;
        int r = s / A, slot = s - r * A;
        bf16x8 v = {};
        if (s < validSegs) {
            int node = idx[segBase + s];
            v = *reinterpret_cast<const bf16x8*>(statesb + (long long)node * 64 + j * 8);
            if (j == 0) Ids[s] = node;
        }
        int byte = (slot * 128 + j * 16) ^ ((r & 7) << 4);
        *reinterpret_cast<bf16x8*>(Xc + r * (2 * D) + byte) = v;
    }
    __syncthreads();

    const int l = tid & 63;
    const int ln = l & 15, kq = l >> 4;
    const int row0 = (tid >> 6) * 16;

    f32x4 acc[NF];
    // ---- layer 1: h = relu(x@W1 + b1)
    #pragma unroll
    for (int n = 0; n < NF; ++n) {
        float b = B1[n * 16 + ln];
        acc[n] = {b, b, b, b};
    }
    {
        const u16* wb = W1t + ln * D + kq * 8;
        #pragma unroll
        for (int kf = 0; kf < KF; ++kf) {
            bf16x8 a = *reinterpret_cast<const bf16x8*>(
                Xc + (row0 + ln) * (2 * D) + ((kf * 64 + kq * 16) ^ ((ln & 7) << 4)));
            #pragma unroll
            for (int n = 0; n < NF; ++n) {
                bf16x8 b = *reinterpret_cast<const bf16x8*>(wb + n * 16 * D + kf * 32);
                acc[n] = __builtin_amdgcn_mfma_f32_16x16x32_bf16(a, b, acc[n], 0, 0, 0);
            }
        }
    }
    // relu -> H into this wave's own rows (wave-local, no barrier)
    #pragma unroll
    for (int n = 0; n < NF; ++n) {
        #pragma unroll
        for (int j = 0; j < 4; ++j) {
            int rl = kq * 4 + j;
            int byte = ((n * 16 + ln) * 2) ^ ((rl & 7) << 4);
            *reinterpret_cast<u16*>(Xc + (row0 + rl) * (2 * D) + byte) =
                f2bf(fmaxf(acc[n][j], 0.f));
        }
    }
    // ---- layer 2 (pre-scaled): acc' = 8*(h@W2 + b2)
    #pragma unroll
    for (int n = 0; n < NF; ++n) {
        float b = 8.f * B2[n * 16 + ln];
        acc[n] = {b, b, b, b};
    }
    {
        const u16* wb = W2t + ln * D + kq * 8;
        #pragma unroll
        for (int kf = 0; kf < KF; ++kf) {
            bf16x8 a = *reinterpret_cast<const bf16x8*>(
                Xc + (row0 + ln) * (2 * D) + ((kf * 64 + kq * 16) ^ ((ln & 7) << 4)));
            #pragma unroll
            for (int n = 0; n < NF; ++n) {
                bf16x8 b = *reinterpret_cast<const bf16x8*>(wb + n * 16 * D + kf * 32);
                acc[n] = __builtin_amdgcn_mfma_f32_16x16x32_bf16(a, b, acc[n], 0, 0, 0);
            }
        }
    }

    // ---- epilogue: block max (plain store) + packed fp16 exp scatter
    float m = -INFINITY;
    #pragma unroll
    for (int n = 0; n < NF; ++n)
        #pragma unroll
        for (int j = 0; j < 4; ++j) {
            int row = row0 + kq * 4 + j;
            if (row < validRows) m = fmaxf(m, acc[n][j]);
        }
    #pragma unroll
    for (int off = 32; off; off >>= 1) m = fmaxf(m, __shfl_xor(m, off));
    if (l == 0) wmax[tid >> 6] = m;
    __syncthreads();
    if (tid == 0)
        blockmax[blockIdx.x] =
            0.125f * fmaxf(fmaxf(wmax[0], wmax[1]), fmaxf(wmax[2], wmax[3]));

    // lane ln holds feat (n*16+ln)&63; neighbor lane ln^1 holds feat^1.
    // Even lanes issue one pk_add_f16 covering (feat, feat+1).
    #pragma unroll
    for (int n = 0; n < NF; ++n) {
        const int slot = n >> 2;
        const int feat = (n * 16 + ln) & 63;
        #pragma unroll
        for (int j = 0; j < 4; ++j) {
            int row = row0 + kq * 4 + j;
            float v = __expf(acc[n][j]);
            float nv = __shfl_xor(v, 1);
            if ((ln & 1) == 0 && row < validRows) {
                int node = Ids[row * A + slot];
                __half2 pk = __halves2half2(__float2half(v), __float2half(nv));
                unsafeAtomicAdd(
                    reinterpret_cast<__half2*>(exps + (long long)node * 64 + feat), pk);
            }
        }
    }
}

// ---------------- global max over block maxima ----------------
__global__ __launch_bounds__(256) void reduce_max(const float* __restrict__ bm,
                                                  int n, float* __restrict__ out) {
    __shared__ float ws_[4];
    float m = -INFINITY;
    for (int i = threadIdx.x; i < n; i += 256) m = fmaxf(m, bm[i]);
    #pragma unroll
    for (int off = 32; off; off >>= 1) m = fmaxf(m, __shfl_xor(m, off));
    if ((threadIdx.x & 63) == 0) ws_[threadIdx.x >> 6] = m;
    __syncthreads();
    if (threadIdx.x == 0)
        out[0] = fmaxf(fmaxf(ws_[0], ws_[1]), fmaxf(ws_[2], ws_[3]));
}

// ---------------- up kernel ----------------
typedef __attribute__((ext_vector_type(8))) _Float16 f16x8;

__global__ __launch_bounds__(256) void up_mfma(
    const u16* __restrict__ statesb, const _Float16* __restrict__ exps,
    const float* __restrict__ gmaxp,
    const u16* __restrict__ W1t, const float* __restrict__ B1,
    const u16* __restrict__ W2t, const float* __restrict__ B2,
    float* __restrict__ outp, int Nn) {
    constexpr int D = 128;
    __shared__ __align__(16) u16 Xs[64 * D];
    char* Xc = (char*)Xs;
    const int tid = threadIdx.x;
    const int block0 = blockIdx.x * 64;
    const int validRows = min(64, Nn - block0);
    const float M = gmaxp[0];
    const float EM = __expf(-8.f * M);

    // X tile: cols 0..63 = max_msg, 64..127 = states
    for (int q = tid; q < 64 * 16; q += 256) {
        int r = q >> 4, p = q & 15;
        bf16x8 v = {};
        if (r < validRows) {
            long long nd = block0 + r;
            if (p < 8) {
                f16x8 s = *reinterpret_cast<const f16x8*>(exps + nd * 64 + p * 8);
                #pragma unroll
                for (int i = 0; i < 8; ++i)
                    v[i] = (short)f2bf(__logf(1e-16f + (float)s[i] * EM) * 0.125f + M);
            } else {
                v = *reinterpret_cast<const bf16x8*>(statesb + nd * 64 + (p - 8) * 8);
            }
        }
        int byte = (p * 16) ^ ((r & 7) << 4);
        *reinterpret_cast<bf16x8*>(Xc + r * 256 + byte) = v;
    }
    __syncthreads();

    const int l = tid & 63;
    const int ln = l & 15, kq = l >> 4;
    const int row0 = (tid >> 6) * 16;

    f32x4 acc[8];
    #pragma unroll
    for (int n = 0; n < 8; ++n) {
        float b = B1[n * 16 + ln];
        acc[n] = {b, b, b, b};
    }
    {
        const u16* wb = W1t + ln * D + kq * 8;
        #pragma unroll
        for (int kf = 0; kf < 4; ++kf) {
            bf16x8 a = *reinterpret_cast<const bf16x8*>(
                Xc + (row0 + ln) * 256 + ((kf * 64 + kq * 16) ^ ((ln & 7) << 4)));
            #pragma unroll
            for (int n = 0; n < 8; ++n) {
                bf16x8 b = *reinterpret_cast<const bf16x8*>(wb + n * 16 * D + kf * 32);
                acc[n] = __builtin_amdgcn_mfma_f32_16x16x32_bf16(a, b, acc[n], 0, 0, 0);
            }
        }
    }
    #pragma unroll
    for (int n = 0; n < 8; ++n) {
        #pragma unroll
        for (int j = 0; j < 4; ++j) {
            int rl = kq * 4 + j;
            int byte = ((n * 16 + ln) * 2) ^ ((rl & 7) << 4);
            *reinterpret_cast<u16*>(Xc + (row0 + rl) * 256 + byte) =
                f2bf(fmaxf(acc[n][j], 0.f));
        }
    }
    f32x4 acc2[4];
    #pragma unroll
    for (int n = 0; n < 4; ++n) {
        float b = B2[n * 16 + ln];
        acc2[n] = {b, b, b, b};
    }
    {
        const u16* wb = W2t + ln * D + kq * 8;   // W2t is [64][128]
        #pragma unroll
        for (int kf = 0; kf < 4; ++kf) {
            bf16x8 a = *reinterpret_cast<const bf16x8*>(
                Xc + (row0 + ln) * 256 + ((kf * 64 + kq * 16) ^ ((ln & 7) << 4)));
            #pragma unroll
            for (int n = 0; n < 4; ++n) {
                bf16x8 b = *reinterpret_cast<const bf16x8*>(wb + n * 16 * D + kf * 32);
                acc2[n] = __builtin_amdgcn_mfma_f32_16x16x32_bf16(a, b, acc2[n], 0, 0, 0);
            }
        }
    }
    #pragma unroll
    for (int n = 0; n < 4; ++n)
        #pragma unroll
        for (int j = 0; j < 4; ++j) {
            int row = row0 + kq * 4 + j;
            if (row < validRows)
                outp[(long long)(block0 + row) * 64 + n * 16 + ln] = acc2[n][j];
        }
}

extern "C" void kernel_launch(void* const* d_in, const int* in_sizes, int n_in,
                              void* d_out, int out_size, void* d_ws, size_t ws_size,
                              hipStream_t stream) {
    const float* states = (const float*)d_in[0];
    const int* idxp[3] = {(const int*)d_in[1], (const int*)d_in[2], (const int*)d_in[3]};
    const float* rw1[3] = {(const float*)d_in[4], (const float*)d_in[8], (const float*)d_in[12]};
    const float* rb1[3] = {(const float*)d_in[5], (const float*)d_in[9], (const float*)d_in[13]};
    const float* rw2[3] = {(const float*)d_in[6], (const float*)d_in[10], (const float*)d_in[14]};
    const float* rb2[3] = {(const float*)d_in[7], (const float*)d_in[11], (const float*)d_in[15]};
    const float* upw1 = (const float*)d_in[16];
    const float* upb1 = (const float*)d_in[17];
    const float* upw2 = (const float*)d_in[18];
    const float* upb2 = (const float*)d_in[19];

    const int N = in_sizes[0] / 64;
    const int E0 = in_sizes[1] / 1;
    const int E1 = in_sizes[2] / 2;
    const int E2 = in_sizes[3] / 3;
    const int G0 = (E0 + 63) / 64, G1 = (E1 + 63) / 64, G2 = (E2 + 63) / 64;
    const int Gtot = G0 + G1 + G2;
    const int Dd[3] = {64, 128, 192};

    size_t off = 0;
    auto alloc = [&](size_t bytes) {
        void* p = (char*)d_ws + off;
        off += (bytes + 255) & ~(size_t)255;
        return p;
    };
    float* gmaxf = (float*)alloc(4);
    float* blockmax = (float*)alloc((size_t)Gtot * 4);
    __half* exps = (__half*)alloc((size_t)N * 64 * 2);
    u16* statesb = (u16*)alloc((size_t)N * 64 * 2);
    u16* w1t[3], *w2t[3];
    for (int r = 0; r < 3; ++r) {
        w1t[r] = (u16*)alloc((size_t)Dd[r] * Dd[r] * 2);
        w2t[r] = (u16*)alloc((size_t)Dd[r] * Dd[r] * 2);
    }
    u16* upw1t = (u16*)alloc(128 * 128 * 2);
    u16* upw2t = (u16*)alloc(64 * 128 * 2);

    // zero exps only (gmaxf/blockmax fully overwritten every launch)
    hipMemsetAsync(exps, 0, (size_t)N * 64 * 2, stream);

    conv_states<<<dim3((N * 64 / 8 + 255) / 256), dim3(256), 0, stream>>>(
        states, statesb, N * 64 / 8);

    TPack tp;
    const float* tsrc[8] = {rw1[0], rw2[0], rw1[1], rw2[1], rw1[2], rw2[2], upw1, upw2};
    u16* tdst[8] = {w1t[0], w2t[0], w1t[1], w2t[1], w1t[2], w2t[2], upw1t, upw2t};
    const int tK[8] = {64, 64, 128, 128, 192, 192, 128, 128};
    const int tN[8] = {64, 64, 128, 128, 192, 192, 128, 64};
    const float tsc[8] = {1.f, 8.f, 1.f, 8.f, 1.f, 8.f, 1.f, 1.f};
    int base = 0;
    for (int i = 0; i < 8; ++i) {
        tp.e[i] = {tsrc[i], tdst[i], tK[i], tN[i], base, tsc[i]};
        base += (tK[i] * tN[i] + 255) / 256;
    }
    transpose_w<<<dim3(base), dim3(256), 0, stream>>>(tp);

    rel_mfma<64><<<dim3(G0), dim3(256), 0, stream>>>(
        statesb, idxp[0], w1t[0], rb1[0], w2t[0], rb2[0], exps, blockmax, E0);
    rel_mfma<128><<<dim3(G1), dim3(256), 0, stream>>>(
        statesb, idxp[1], w1t[1], rb1[1], w2t[1], rb2[1], exps, blockmax + G0, E1);
    rel_mfma<192><<<dim3(G2), dim3(256), 0, stream>>>(
        statesb, idxp[2], w1t[2], rb1[2], w2t[2], rb2[2], exps, blockmax + G0 + G1, E2);

    reduce_max<<<dim3(1), dim3(256), 0, stream>>>(blockmax, Gtot, gmaxf);

    up_mfma<<<dim3((N + 63) / 64), dim3(256), 0, stream>>>(
        statesb, (const _Float16*)exps, gmaxf, upw1t, upb1, upw2t, upb2,
        (float*)d_out, N);
}

// Round 9
// 542.814 us; speedup vs baseline: 2.5851x; 1.3854x over previous
//
#include <hip/hip_runtime.h>
#include <hip/hip_fp16.h>
#include <math.h>

// RelationMessagePassing — bf16 MFMA, N-split waves (4x less weight traffic),
// packed-fp16 atomic scatter.  (Round-8 fix: missing _Float16 cast.)
//
// Round-7 finding: halving atomic ops changed nothing -> not atomic-bound.
// Byte audit: weight re-reads dominated (each wave streamed full W1t+W2t
// from L2 per block: 4.0 GB total vs 0.3 GB gather). Fix: wave w owns output
// cols [w*D/4,(w+1)*D/4) for ALL 64 rows => weights read once per block.
// Inner loop: 4 ds_read + NFW weight loads + 4*NFW MFMA per kf.
//
// Pipeline: memset exps(fp16) | conv_states | transpose_w (W2 pre-scaled 8) |
//   rel_mfma<64/128/192>: gather->L1->bar->H->bar->L2 -> blockmax store +
//     pk_f16 atomic exp(acc') -> reduce_max |
//   up_mfma: max_msg = log(1e-16+S*e^-8M)/8+M; concat; MFMA; fp32 out.

typedef __attribute__((ext_vector_type(8))) short bf16x8;
typedef __attribute__((ext_vector_type(4))) float f32x4;
typedef __attribute__((ext_vector_type(8))) _Float16 f16x8;
typedef unsigned short u16;

__device__ __forceinline__ u16 f2bf(float f) {   // RNE f32->bf16 (finite)
    unsigned u = __float_as_uint(f);
    return (u16)((u + 0x7fffu + ((u >> 16) & 1u)) >> 16);
}

// ---------------- prep ----------------
__global__ __launch_bounds__(256) void conv_states(const float* __restrict__ src,
                                                   u16* __restrict__ dst, int n8) {
    int i = blockIdx.x * 256 + threadIdx.x;
    if (i >= n8) return;
    float4 a = reinterpret_cast<const float4*>(src)[2 * i];
    float4 b = reinterpret_cast<const float4*>(src)[2 * i + 1];
    bf16x8 v;
    v[0] = (short)f2bf(a.x); v[1] = (short)f2bf(a.y);
    v[2] = (short)f2bf(a.z); v[3] = (short)f2bf(a.w);
    v[4] = (short)f2bf(b.x); v[5] = (short)f2bf(b.y);
    v[6] = (short)f2bf(b.z); v[7] = (short)f2bf(b.w);
    reinterpret_cast<bf16x8*>(dst)[i] = v;
}

struct TEnt { const float* src; u16* dst; int K, N, base; float scale; };
struct TPack { TEnt e[8]; };
// dst[n*K + k] = bf16(scale * src[k*N + n])
__global__ __launch_bounds__(256) void transpose_w(TPack p) {
    int b = blockIdx.x;
    int i = 0;
    while (i < 7 && b >= p.e[i + 1].base) ++i;
    TEnt e = p.e[i];
    int idx = (b - e.base) * 256 + threadIdx.x;
    if (idx < e.K * e.N) {
        int n = idx / e.K, k = idx - n * e.K;
        e.dst[idx] = f2bf(e.scale * e.src[k * e.N + n]);
    }
}

// ---------------- relation kernels ----------------
// D = arity*64; block = 64 tuples, 4 waves; wave w owns cols [w*D/4,(w+1)*D/4)
// for all 64 rows. Layer2 pre-scaled by 8 => acc' = 8*o.
template <int D>
__global__ __launch_bounds__(256) void rel_mfma(
    const u16* __restrict__ statesb, const int* __restrict__ idx,
    const u16* __restrict__ W1t, const float* __restrict__ B1,
    const u16* __restrict__ W2t, const float* __restrict__ B2,
    __half* __restrict__ exps, float* __restrict__ blockmax, int E) {
    constexpr int A = D / 64;
    constexpr int KF = D / 32;
    constexpr int NFW = D / 64;          // N-frags per wave (D/4 cols)
    __shared__ __align__(16) u16 Xs[64 * D];
    __shared__ int Ids[64 * A];
    __shared__ float wmax[4];
    char* Xc = (char*)Xs;

    const int tid = threadIdx.x;
    const int block0 = blockIdx.x * 64;
    const int validRows = min(64, E - block0);
    const int validSegs = validRows * A;
    const long long segBase = (long long)block0 * A;

    // gather: seg s -> row s/A, col-block (s%A); XOR-swizzled LDS rows
    for (int q = tid; q < 64 * A * 8; q += 256) {
        int s = q >> 3, j = q & 7;
        int r = s / A, slot = s - r * A;
        bf16x8 v = {};
        if (s < validSegs) {
            int node = idx[segBase + s];
            v = *reinterpret_cast<const bf16x8*>(statesb + (long long)node * 64 + j * 8);
            if (j == 0) Ids[s] = node;
        }
        int byte = (slot * 128 + j * 16) ^ ((r & 7) << 4);
        *reinterpret_cast<bf16x8*>(Xc + r * (2 * D) + byte) = v;
    }
    __syncthreads();

    const int l = tid & 63;
    const int ln = l & 15, kq = l >> 4;
    const int w = tid >> 6;
    const int nbase = w * NFW;           // global N-frag base for this wave

    f32x4 acc[4][NFW];

    // ---- layer 1: h = relu(x@W1 + b1), wave computes its col slice x 64 rows
    #pragma unroll
    for (int nf = 0; nf < NFW; ++nf) {
        float b = B1[(nbase + nf) * 16 + ln];
        #pragma unroll
        for (int m = 0; m < 4; ++m) acc[m][nf] = {b, b, b, b};
    }
    #pragma unroll
    for (int kf = 0; kf < KF; ++kf) {
        bf16x8 a[4];
        #pragma unroll
        for (int m = 0; m < 4; ++m)
            a[m] = *reinterpret_cast<const bf16x8*>(
                Xc + (m * 16 + ln) * (2 * D) + ((kf * 64 + kq * 16) ^ ((ln & 7) << 4)));
        #pragma unroll
        for (int nf = 0; nf < NFW; ++nf) {
            bf16x8 b = *reinterpret_cast<const bf16x8*>(
                W1t + ((nbase + nf) * 16 + ln) * D + kf * 32 + kq * 8);
            #pragma unroll
            for (int m = 0; m < 4; ++m)
                acc[m][nf] = __builtin_amdgcn_mfma_f32_16x16x32_bf16(a[m], b, acc[m][nf], 0, 0, 0);
        }
    }
    __syncthreads();   // all waves done reading X
    // relu -> H (this wave's col slice, all 64 rows)
    #pragma unroll
    for (int nf = 0; nf < NFW; ++nf) {
        const int c = (nbase + nf) * 16 + ln;
        #pragma unroll
        for (int m = 0; m < 4; ++m)
            #pragma unroll
            for (int j = 0; j < 4; ++j) {
                int row = m * 16 + kq * 4 + j;
                int byte = (c * 2) ^ ((row & 7) << 4);
                *reinterpret_cast<u16*>(Xc + row * (2 * D) + byte) =
                    f2bf(fmaxf(acc[m][nf][j], 0.f));
            }
    }
    __syncthreads();   // H complete

    // ---- layer 2 (pre-scaled): acc' = 8*(h@W2 + b2)
    #pragma unroll
    for (int nf = 0; nf < NFW; ++nf) {
        float b = 8.f * B2[(nbase + nf) * 16 + ln];
        #pragma unroll
        for (int m = 0; m < 4; ++m) acc[m][nf] = {b, b, b, b};
    }
    #pragma unroll
    for (int kf = 0; kf < KF; ++kf) {
        bf16x8 a[4];
        #pragma unroll
        for (int m = 0; m < 4; ++m)
            a[m] = *reinterpret_cast<const bf16x8*>(
                Xc + (m * 16 + ln) * (2 * D) + ((kf * 64 + kq * 16) ^ ((ln & 7) << 4)));
        #pragma unroll
        for (int nf = 0; nf < NFW; ++nf) {
            bf16x8 b = *reinterpret_cast<const bf16x8*>(
                W2t + ((nbase + nf) * 16 + ln) * D + kf * 32 + kq * 8);
            #pragma unroll
            for (int m = 0; m < 4; ++m)
                acc[m][nf] = __builtin_amdgcn_mfma_f32_16x16x32_bf16(a[m], b, acc[m][nf], 0, 0, 0);
        }
    }

    // ---- epilogue: block max (plain store) + packed fp16 exp scatter
    float m = -INFINITY;
    #pragma unroll
    for (int mf = 0; mf < 4; ++mf)
        #pragma unroll
        for (int nf = 0; nf < NFW; ++nf)
            #pragma unroll
            for (int j = 0; j < 4; ++j) {
                int row = mf * 16 + kq * 4 + j;
                if (row < validRows) m = fmaxf(m, acc[mf][nf][j]);
            }
    #pragma unroll
    for (int off = 32; off; off >>= 1) m = fmaxf(m, __shfl_xor(m, off));
    if (l == 0) wmax[w] = m;
    __syncthreads();
    if (tid == 0)
        blockmax[blockIdx.x] =
            0.125f * fmaxf(fmaxf(wmax[0], wmax[1]), fmaxf(wmax[2], wmax[3]));

    // even lanes issue one pk_add_f16 covering (feat, feat+1)
    #pragma unroll
    for (int nf = 0; nf < NFW; ++nf) {
        const int c = (nbase + nf) * 16 + ln;
        const int slot = c >> 6;
        const int feat = c & 63;
        #pragma unroll
        for (int mf = 0; mf < 4; ++mf)
            #pragma unroll
            for (int j = 0; j < 4; ++j) {
                int row = mf * 16 + kq * 4 + j;
                float v = __expf(acc[mf][nf][j]);
                float nv = __shfl_xor(v, 1);
                if ((ln & 1) == 0 && row < validRows) {
                    int node = Ids[row * A + slot];
                    __half2 pk = __halves2half2(__float2half(v), __float2half(nv));
                    unsafeAtomicAdd(
                        reinterpret_cast<__half2*>(exps + (long long)node * 64 + feat), pk);
                }
            }
    }
}

// ---------------- global max over block maxima ----------------
__global__ __launch_bounds__(256) void reduce_max(const float* __restrict__ bm,
                                                  int n, float* __restrict__ out) {
    __shared__ float ws_[4];
    float m = -INFINITY;
    for (int i = threadIdx.x; i < n; i += 256) m = fmaxf(m, bm[i]);
    #pragma unroll
    for (int off = 32; off; off >>= 1) m = fmaxf(m, __shfl_xor(m, off));
    if ((threadIdx.x & 63) == 0) ws_[threadIdx.x >> 6] = m;
    __syncthreads();
    if (threadIdx.x == 0)
        out[0] = fmaxf(fmaxf(ws_[0], ws_[1]), fmaxf(ws_[2], ws_[3]));
}

// ---------------- up kernel ----------------
__global__ __launch_bounds__(256) void up_mfma(
    const u16* __restrict__ statesb, const _Float16* __restrict__ exps,
    const float* __restrict__ gmaxp,
    const u16* __restrict__ W1t, const float* __restrict__ B1,
    const u16* __restrict__ W2t, const float* __restrict__ B2,
    float* __restrict__ outp, int Nn) {
    constexpr int D = 128;
    __shared__ __align__(16) u16 Xs[64 * D];
    char* Xc = (char*)Xs;
    const int tid = threadIdx.x;
    const int block0 = blockIdx.x * 64;
    const int validRows = min(64, Nn - block0);
    const float M = gmaxp[0];
    const float EM = __expf(-8.f * M);

    // X tile: cols 0..63 = max_msg, 64..127 = states
    for (int q = tid; q < 64 * 16; q += 256) {
        int r = q >> 4, p = q & 15;
        bf16x8 v = {};
        if (r < validRows) {
            long long nd = block0 + r;
            if (p < 8) {
                f16x8 s = *reinterpret_cast<const f16x8*>(exps + nd * 64 + p * 8);
                #pragma unroll
                for (int i = 0; i < 8; ++i)
                    v[i] = (short)f2bf(__logf(1e-16f + (float)s[i] * EM) * 0.125f + M);
            } else {
                v = *reinterpret_cast<const bf16x8*>(statesb + nd * 64 + (p - 8) * 8);
            }
        }
        int byte = (p * 16) ^ ((r & 7) << 4);
        *reinterpret_cast<bf16x8*>(Xc + r * 256 + byte) = v;
    }
    __syncthreads();

    const int l = tid & 63;
    const int ln = l & 15, kq = l >> 4;
    const int row0 = (tid >> 6) * 16;

    f32x4 acc[8];
    #pragma unroll
    for (int n = 0; n < 8; ++n) {
        float b = B1[n * 16 + ln];
        acc[n] = {b, b, b, b};
    }
    {
        const u16* wb = W1t + ln * D + kq * 8;
        #pragma unroll
        for (int kf = 0; kf < 4; ++kf) {
            bf16x8 a = *reinterpret_cast<const bf16x8*>(
                Xc + (row0 + ln) * 256 + ((kf * 64 + kq * 16) ^ ((ln & 7) << 4)));
            #pragma unroll
            for (int n = 0; n < 8; ++n) {
                bf16x8 b = *reinterpret_cast<const bf16x8*>(wb + n * 16 * D + kf * 32);
                acc[n] = __builtin_amdgcn_mfma_f32_16x16x32_bf16(a, b, acc[n], 0, 0, 0);
            }
        }
    }
    #pragma unroll
    for (int n = 0; n < 8; ++n) {
        #pragma unroll
        for (int j = 0; j < 4; ++j) {
            int rl = kq * 4 + j;
            int byte = ((n * 16 + ln) * 2) ^ ((rl & 7) << 4);
            *reinterpret_cast<u16*>(Xc + (row0 + rl) * 256 + byte) =
                f2bf(fmaxf(acc[n][j], 0.f));
        }
    }
    f32x4 acc2[4];
    #pragma unroll
    for (int n = 0; n < 4; ++n) {
        float b = B2[n * 16 + ln];
        acc2[n] = {b, b, b, b};
    }
    {
        const u16* wb = W2t + ln * D + kq * 8;   // W2t is [64][128]
        #pragma unroll
        for (int kf = 0; kf < 4; ++kf) {
            bf16x8 a = *reinterpret_cast<const bf16x8*>(
                Xc + (row0 + ln) * 256 + ((kf * 64 + kq * 16) ^ ((ln & 7) << 4)));
            #pragma unroll
            for (int n = 0; n < 4; ++n) {
                bf16x8 b = *reinterpret_cast<const bf16x8*>(wb + n * 16 * D + kf * 32);
                acc2[n] = __builtin_amdgcn_mfma_f32_16x16x32_bf16(a, b, acc2[n], 0, 0, 0);
            }
        }
    }
    #pragma unroll
    for (int n = 0; n < 4; ++n)
        #pragma unroll
        for (int j = 0; j < 4; ++j) {
            int row = row0 + kq * 4 + j;
            if (row < validRows)
                outp[(long long)(block0 + row) * 64 + n * 16 + ln] = acc2[n][j];
        }
}

extern "C" void kernel_launch(void* const* d_in, const int* in_sizes, int n_in,
                              void* d_out, int out_size, void* d_ws, size_t ws_size,
                              hipStream_t stream) {
    const float* states = (const float*)d_in[0];
    const int* idxp[3] = {(const int*)d_in[1], (const int*)d_in[2], (const int*)d_in[3]};
    const float* rw1[3] = {(const float*)d_in[4], (const float*)d_in[8], (const float*)d_in[12]};
    const float* rb1[3] = {(const float*)d_in[5], (const float*)d_in[9], (const float*)d_in[13]};
    const float* rw2[3] = {(const float*)d_in[6], (const float*)d_in[10], (const float*)d_in[14]};
    const float* rb2[3] = {(const float*)d_in[7], (const float*)d_in[11], (const float*)d_in[15]};
    const float* upw1 = (const float*)d_in[16];
    const float* upb1 = (const float*)d_in[17];
    const float* upw2 = (const float*)d_in[18];
    const float* upb2 = (const float*)d_in[19];

    const int N = in_sizes[0] / 64;
    const int E0 = in_sizes[1] / 1;
    const int E1 = in_sizes[2] / 2;
    const int E2 = in_sizes[3] / 3;
    const int G0 = (E0 + 63) / 64, G1 = (E1 + 63) / 64, G2 = (E2 + 63) / 64;
    const int Gtot = G0 + G1 + G2;
    const int Dd[3] = {64, 128, 192};

    size_t off = 0;
    auto alloc = [&](size_t bytes) {
        void* p = (char*)d_ws + off;
        off += (bytes + 255) & ~(size_t)255;
        return p;
    };
    float* gmaxf = (float*)alloc(4);
    float* blockmax = (float*)alloc((size_t)Gtot * 4);
    __half* exps = (__half*)alloc((size_t)N * 64 * 2);
    u16* statesb = (u16*)alloc((size_t)N * 64 * 2);
    u16* w1t[3], *w2t[3];
    for (int r = 0; r < 3; ++r) {
        w1t[r] = (u16*)alloc((size_t)Dd[r] * Dd[r] * 2);
        w2t[r] = (u16*)alloc((size_t)Dd[r] * Dd[r] * 2);
    }
    u16* upw1t = (u16*)alloc(128 * 128 * 2);
    u16* upw2t = (u16*)alloc(64 * 128 * 2);

    // zero exps only (gmaxf/blockmax fully overwritten every launch)
    (void)hipMemsetAsync(exps, 0, (size_t)N * 64 * 2, stream);

    conv_states<<<dim3((N * 64 / 8 + 255) / 256), dim3(256), 0, stream>>>(
        states, statesb, N * 64 / 8);

    TPack tp;
    const float* tsrc[8] = {rw1[0], rw2[0], rw1[1], rw2[1], rw1[2], rw2[2], upw1, upw2};
    u16* tdst[8] = {w1t[0], w2t[0], w1t[1], w2t[1], w1t[2], w2t[2], upw1t, upw2t};
    const int tK[8] = {64, 64, 128, 128, 192, 192, 128, 128};
    const int tN[8] = {64, 64, 128, 128, 192, 192, 128, 64};
    const float tsc[8] = {1.f, 8.f, 1.f, 8.f, 1.f, 8.f, 1.f, 1.f};
    int base = 0;
    for (int i = 0; i < 8; ++i) {
        tp.e[i] = {tsrc[i], tdst[i], tK[i], tN[i], base, tsc[i]};
        base += (tK[i] * tN[i] + 255) / 256;
    }
    transpose_w<<<dim3(base), dim3(256), 0, stream>>>(tp);

    rel_mfma<64><<<dim3(G0), dim3(256), 0, stream>>>(
        statesb, idxp[0], w1t[0], rb1[0], w2t[0], rb2[0], exps, blockmax, E0);
    rel_mfma<128><<<dim3(G1), dim3(256), 0, stream>>>(
        statesb, idxp[1], w1t[1], rb1[1], w2t[1], rb2[1], exps, blockmax + G0, E1);
    rel_mfma<192><<<dim3(G2), dim3(256), 0, stream>>>(
        statesb, idxp[2], w1t[2], rb1[2], w2t[2], rb2[2], exps, blockmax + G0 + G1, E2);

    reduce_max<<<dim3(1), dim3(256), 0, stream>>>(blockmax, Gtot, gmaxf);

    up_mfma<<<dim3((N + 63) / 64), dim3(256), 0, stream>>>(
        statesb, (const _Float16*)exps, gmaxf, upw1t, upb1, upw2t, upb2,
        (float*)d_out, N);
}